// Round 1
// baseline (281.525 us; speedup 1.0000x reference)
//
#include <hip/hip_runtime.h>
#include <hip/hip_bf16.h>

#define BATCH 32768
#define SEQ 512
#define EPS 1e-8f

// One thread per batch row. Reverse scan over t, 4 timesteps per iteration.
// rewards/dones/out rows are 2048B-strided -> float4 clean.
// values rows are 2052B-strided -> scalar loads.
__global__ void __launch_bounds__(64)
gamma_lambda_scan(const float* __restrict__ values,
                  const float* __restrict__ rewards,
                  const float* __restrict__ dones,
                  const float* __restrict__ raw_gamma,
                  const float* __restrict__ raw_lambd,
                  float* __restrict__ out) {
    __shared__ float s_lam[SEQ];
    const int tid = threadIdx.x;

    // Stage lambdas = max(tanh(raw_lambd), eps) into LDS (8 per thread @64 thr)
    for (int i = tid; i < SEQ; i += blockDim.x) {
        s_lam[i] = fmaxf(tanhf(raw_lambd[i]), EPS);
    }
    __syncthreads();

    const float gamma = fmaxf(tanhf(raw_gamma[0]), EPS);

    const int b = blockIdx.x * blockDim.x + tid;
    const float* __restrict__ vrow = values  + (size_t)b * (SEQ + 1);
    const float* __restrict__ rrow = rewards + (size_t)b * SEQ;
    const float* __restrict__ drow = dones   + (size_t)b * SEQ;
    float*       __restrict__ orow = out     + (size_t)b * SEQ;

    float ret = vrow[SEQ];  // init = values[:, -1]

    #pragma unroll 4
    for (int T = SEQ - 4; T >= 0; T -= 4) {
        const float4 r4 = *(const float4*)(rrow + T);
        const float4 d4 = *(const float4*)(drow + T);
        const float v1 = vrow[T + 1];
        const float v2 = vrow[T + 2];
        const float v3 = vrow[T + 3];
        const float v4 = vrow[T + 4];
        const float l0 = s_lam[T + 0];
        const float l1 = s_lam[T + 1];
        const float l2 = s_lam[T + 2];
        const float l3 = s_lam[T + 3];

        // t = T+3
        float boot = (1.f - l3) * v4 + l3 * ret;
        ret = fmaf(gamma * (1.f - d4.w), boot, r4.w);
        const float o3 = ret;
        // t = T+2
        boot = (1.f - l2) * v3 + l2 * ret;
        ret = fmaf(gamma * (1.f - d4.z), boot, r4.z);
        const float o2 = ret;
        // t = T+1
        boot = (1.f - l1) * v2 + l1 * ret;
        ret = fmaf(gamma * (1.f - d4.y), boot, r4.y);
        const float o1 = ret;
        // t = T
        boot = (1.f - l0) * v1 + l0 * ret;
        ret = fmaf(gamma * (1.f - d4.x), boot, r4.x);
        const float o0 = ret;

        *(float4*)(orow + T) = make_float4(o0, o1, o2, o3);
    }
}

extern "C" void kernel_launch(void* const* d_in, const int* in_sizes, int n_in,
                              void* d_out, int out_size, void* d_ws, size_t ws_size,
                              hipStream_t stream) {
    const float* values    = (const float*)d_in[0];
    const float* rewards   = (const float*)d_in[1];
    const float* dones     = (const float*)d_in[2];
    const float* raw_gamma = (const float*)d_in[3];
    const float* raw_lambd = (const float*)d_in[4];
    float* out = (float*)d_out;

    const int block = 64;
    const int grid = BATCH / block;  // 512 blocks
    gamma_lambda_scan<<<grid, block, 0, stream>>>(
        values, rewards, dones, raw_gamma, raw_lambd, out);
}